// Round 6
// baseline (214.939 us; speedup 1.0000x reference)
//
#include <hip/hip_runtime.h>
#include <hip/hip_bf16.h>

typedef __bf16 bf16x8 __attribute__((ext_vector_type(8)));
typedef float  f32x16 __attribute__((ext_vector_type(16)));
typedef float  f32x4  __attribute__((ext_vector_type(4)));
typedef float  f32x2  __attribute__((ext_vector_type(2)));

static __device__ __forceinline__ f32x16 mfma32(bf16x8 a, bf16x8 b, f32x16 c) {
    return __builtin_amdgcn_mfma_f32_32x32x16_bf16(a, b, c, 0, 0, 0);
}

// gelu-tanh via sigmoid with log2e folded in:
// gelu(h) = h / (1 + exp2(-h*(C1 + C2*h^2)))
#define GELU_C1 2.30220820f
#define GELU_C2 0.10294324f

// ---------------------------------------------------------------------------
// Pack kernel: W1p (K=144, bias folded), W2p (sigma-permuted), fp64 router
// weights (unchanged from round 5).
// ---------------------------------------------------------------------------
__global__ __launch_bounds__(256) void pack_kernel(
    const float* __restrict__ We1, const float* __restrict__ be1,
    const float* __restrict__ Ws1, const float* __restrict__ bs1,
    const float* __restrict__ We2, const float* __restrict__ Ws2,
    const float* __restrict__ Wr1, const float* __restrict__ br1,
    const float* __restrict__ Wr2, const float* __restrict__ br2,
    __bf16* __restrict__ w1p, __bf16* __restrict__ w2p,
    double* __restrict__ wr1d, double* __restrict__ br1d,
    double* __restrict__ wr2d, double* __restrict__ br2d)
{
    int tid = blockIdx.x * 256 + threadIdx.x;
    if (tid < 23040) {
        int l  = tid & 63;
        int ks = (tid >> 6) % 9;
        int nt = (tid / 576) & 3;
        int e  = tid / 2304;
        const float* src = (e < 8) ? (We1 + e * 16384) : (Ws1 + (e - 8) * 16384);
        const float* bia = (e < 8) ? (be1 + e * 128)   : (bs1 + (e - 8) * 128);
        int n = nt * 32 + (l & 31);
        int kb = ks * 16 + (l >> 5) * 8;
        bf16x8 v;
        #pragma unroll
        for (int j = 0; j < 8; ++j) {
            int k = kb + j;
            float f = (k < 128) ? src[k * 128 + n] : ((k == 128) ? bia[n] : 0.f);
            v[j] = (__bf16)f;
        }
        *(bf16x8*)(w1p + (size_t)tid * 8) = v;
    } else if (tid < 43520) {
        int t2 = tid - 23040;
        int l  = t2 & 63;
        int ks = (t2 >> 6) & 7;
        int ot = (t2 / 512) & 3;
        int e  = t2 / 2048;
        const float* src = (e < 8) ? (We2 + e * 16384) : (Ws2 + (e - 8) * 16384);
        int o  = ot * 32 + (l & 31);
        int lh = l >> 5;
        bf16x8 v;
        #pragma unroll
        for (int j = 0; j < 8; ++j) {
            int hid = 16 * ks + 8 * (j >> 2) + 4 * lh + (j & 3);
            v[j] = (__bf16)src[hid * 128 + o];
        }
        *(bf16x8*)(w2p + (size_t)t2 * 8) = v;
    } else if (tid < 45568) {
        int i = tid - 43520;            // 0..2047: Wr1 [128][16]
        wr1d[i] = (double)Wr1[i];
    } else if (tid < 45696) {
        int i = tid - 45568;            // 0..127: Wr2 [16][8]
        wr2d[i] = (double)Wr2[i];
    } else if (tid < 45712) {
        int i = tid - 45696;            // 0..15
        br1d[i] = (double)br1[i];
    } else if (tid < 45720) {
        int i = tid - 45712;            // 0..7
        br2d[i] = (double)br2[i];
    }
}

// ---------------------------------------------------------------------------
// Fused MoE kernel, occupancy-3 layout. 64 tokens per block, 4 waves.
// LDS 51,968 B: Xp [0,18432) | xs [18432,51968) stride-131 fp32.
// Overlays: rfs -> [18432,26624) after xs reads done; mgs -> [49920,51968);
// Red -> [0,32768) after expert loop (Xp dead, mgs untouched).
// ---------------------------------------------------------------------------
__global__ __launch_bounds__(256, 3) void moe_main_kernel(
    const float* __restrict__ x,
    const double* __restrict__ wr1d, const double* __restrict__ br1d,
    const double* __restrict__ wr2d, const double* __restrict__ br2d,
    const __bf16* __restrict__ w1p, const __bf16* __restrict__ w2p,
    const float* __restrict__ be2, const float* __restrict__ bs2,
    float* __restrict__ out)
{
    __shared__ __align__(16) char lds[51968];
    __bf16* Xp  = (__bf16*)lds;                // 18432 B
    float*  xs  = (float*)(lds + 18432);       // 64 rows * 131 f32 = 33536 B
    double* rfs = (double*)(lds + 18432);      // overlay on xs (after L1)
    float*  mgs = (float*)(lds + 49920);       // 2048 B, tail of xs
    float*  Red = (float*)lds;                 // 32768 B overlay after loop

    const int t    = threadIdx.x;
    const int lane = t & 63;
    const int wave = t >> 6;
    const int l31  = lane & 31;
    const int lh   = lane >> 5;
    const int mt   = wave >> 1;
    const int h    = wave & 1;
    const int tok0 = blockIdx.x * 64;

    // ---- stage X: one global read builds fp32 xs (stride 131) + bf16 Xp ----
    #pragma unroll
    for (int i = 0; i < 4; ++i) {
        int g = i * 256 + t;       // 8-element group id, 0..1023
        int m = g >> 4;            // token 0..63
        int c = g & 15;            // which 8-k chunk
        const f32x4* sp = (const f32x4*)(x + (size_t)(tok0 + m) * 128 + c * 8);
        f32x4 va = sp[0], vb = sp[1];
        float* xd = xs + m * 131 + c * 8;
        xd[0] = va[0]; xd[1] = va[1]; xd[2] = va[2]; xd[3] = va[3];
        xd[4] = vb[0]; xd[5] = vb[1]; xd[6] = vb[2]; xd[7] = vb[3];
        bf16x8 v;
        v[0]=(__bf16)va[0]; v[1]=(__bf16)va[1]; v[2]=(__bf16)va[2]; v[3]=(__bf16)va[3];
        v[4]=(__bf16)vb[0]; v[5]=(__bf16)vb[1]; v[6]=(__bf16)vb[2]; v[7]=(__bf16)vb[3];
        *(bf16x8*)&Xp[(((m >> 5) * 9 + (c >> 1)) * 64 + (c & 1) * 32 + (m & 31)) * 8] = v;
    }
    // ks=8 bias column: k=128 -> 1.0, k=129..143 -> 0
    if (t < 128) {
        int mtx = t >> 6, l = t & 63;
        bf16x8 v;
        #pragma unroll
        for (int j = 0; j < 8; ++j) v[j] = (__bf16)0.f;
        if (l < 32) v[0] = (__bf16)1.0f;
        *(bf16x8*)&Xp[((mtx * 9 + 8) * 64 + l) * 8] = v;
    }
    __syncthreads();

    // ---- router layer 1 (fp64): thread (tok=t&63, rq=(t>>6)*4) -> 4 rf ----
    double rf4[4];
    {
        const int tok = t & 63;
        const int rqs = __builtin_amdgcn_readfirstlane((t >> 6) * 4);
        #pragma unroll
        for (int j = 0; j < 4; ++j) rf4[j] = br1d[rqs + j];
        const float* xr = xs + tok * 131;   // odd stride: 2-way banks = free
        #pragma unroll 8
        for (int k = 0; k < 128; ++k) {
            double xv = (double)xr[k];
            #pragma unroll
            for (int j = 0; j < 4; ++j)
                rf4[j] = fma(xv, wr1d[k * 16 + rqs + j], rf4[j]);
        }
        #pragma unroll
        for (int j = 0; j < 4; ++j) rf4[j] = rf4[j] > 0.0 ? rf4[j] : 0.0;
    }
    __syncthreads();   // xs reads complete -> rfs overlay safe

    {
        const int tok = t & 63;
        const int rq  = (t >> 6) * 4;
        #pragma unroll
        for (int j = 0; j < 4; ++j) rfs[tok * 16 + rq + j] = rf4[j];
    }
    __syncthreads();

    // ---- router layer 2 + softmax + div-free mask (fp64), 1 thr/token ----
    if (t < 64) {
        double lg[8];
        #pragma unroll
        for (int j = 0; j < 8; ++j) lg[j] = br2d[j];
        #pragma unroll
        for (int r = 0; r < 16; ++r) {
            double rv = rfs[t * 16 + r];
            #pragma unroll
            for (int j = 0; j < 8; ++j)
                lg[j] = fma(rv, wr2d[r * 8 + j], lg[j]);
        }
        double mx = lg[0];
        #pragma unroll
        for (int j = 1; j < 8; ++j) mx = lg[j] > mx ? lg[j] : mx;
        double ex[8]; double s = 0.0;
        #pragma unroll
        for (int j = 0; j < 8; ++j) { ex[j] = exp(lg[j] - mx); s += ex[j]; }
        // mask: g > 1/8  <=>  8*ex[j] > s
        double ms = 0.0;
        bool mk[8];
        #pragma unroll
        for (int j = 0; j < 8; ++j) {
            mk[j] = (8.0 * ex[j] > s);
            ms += mk[j] ? ex[j] : 0.0;
        }
        double inv = 1.0 / (ms + s * 1e-8);
        #pragma unroll
        for (int j = 0; j < 8; ++j)
            mgs[t * 8 + j] = mk[j] ? (float)(ex[j] * inv) : 0.f;
    }
    __syncthreads();

    // ---- per-token gates for this wave's token tile ----
    const float* mgr = mgs + (32 * mt + l31) * 8;
    f32x4 ga4 = *(const f32x4*)mgr;
    f32x4 gb4 = *(const f32x4*)(mgr + 4);
    float gte[8] = {ga4[0], ga4[1], ga4[2], ga4[3], gb4[0], gb4[1], gb4[2], gb4[3]};

    f32x16 acc[4];
    #pragma unroll
    for (int ot = 0; ot < 4; ++ot)
        #pragma unroll
        for (int i = 0; i < 16; ++i) acc[ot][i] = 0.f;

    const bf16x8* w1v = (const bf16x8*)w1p;
    const bf16x8* w2v = (const bf16x8*)w2p;

    #pragma unroll 1
    for (int e = 0; e < 10; ++e) {
        const float gv = (e < 8) ? gte[e] : 1.0f;
        #pragma unroll
        for (int n2 = 0; n2 < 2; ++n2) {
            // W1^T A-frags for n-tile (2h + n2): single-buffered; the stall on
            // the first frag is covered by the 3rd co-resident wave.
            const bf16x8* wap = w1v + ((size_t)(e * 4 + 2 * h + n2) * 9) * 64 + lane;
            bf16x8 wb[9];
            #pragma unroll
            for (int ks = 0; ks < 9; ++ks) wb[ks] = wap[ks * 64];

            // W2 B-frags for this phase (hidden under GEMM1)
            const bf16x8* wBp = w2v + ((size_t)(e * 4) * 8 + 4 * h + 2 * n2) * 64 + lane;
            bf16x8 wBc[8];
            #pragma unroll
            for (int ot = 0; ot < 4; ++ot)
                #pragma unroll
                for (int b = 0; b < 2; ++b)
                    wBc[ot * 2 + b] = wBp[(ot * 8 + b) * 64];

            // GEMM1 phase
            f32x16 a1;
            #pragma unroll
            for (int i = 0; i < 16; ++i) a1[i] = 0.f;
            #pragma unroll
            for (int ks = 0; ks < 9; ++ks) {
                bf16x8 xb = *(const bf16x8*)&Xp[((mt * 9 + ks) * 64 + lane) * 8];
                a1 = mfma32(wb[ks], xb, a1);
            }

            // gelu + gate -> A-frags -> GEMM2
            #pragma unroll
            for (int b = 0; b < 2; ++b) {
                bf16x8 fr;
                #pragma unroll
                for (int jp = 0; jp < 4; ++jp) {
                    f32x2 hh; hh[0] = a1[8 * b + 2 * jp]; hh[1] = a1[8 * b + 2 * jp + 1];
                    f32x2 tt = hh * hh;
                    f32x2 pp;
                    pp[0] = fmaf(tt[0], -GELU_C2, -GELU_C1);
                    pp[1] = fmaf(tt[1], -GELU_C2, -GELU_C1);
                    f32x2 mm = hh * pp;
                    float e0 = __builtin_amdgcn_exp2f(mm[0]);
                    float e1 = __builtin_amdgcn_exp2f(mm[1]);
                    float q0 = __builtin_amdgcn_rcpf(1.f + e0);
                    float q1 = __builtin_amdgcn_rcpf(1.f + e1);
                    f32x2 gg; gg[0] = hh[0] * q0 * gv; gg[1] = hh[1] * q1 * gv;
                    fr[2 * jp]     = (__bf16)gg[0];
                    fr[2 * jp + 1] = (__bf16)gg[1];
                }
                acc[0] = mfma32(fr, wBc[0 * 2 + b], acc[0]);
                acc[1] = mfma32(fr, wBc[1 * 2 + b], acc[1]);
                acc[2] = mfma32(fr, wBc[2 * 2 + b], acc[2]);
                acc[3] = mfma32(fr, wBc[3 * 2 + b], acc[3]);
            }
        }
    }

    __syncthreads();   // Xp/xs dead; Red overlay safe (mgs untouched)
    if (h == 1) {
        #pragma unroll
        for (int ot = 0; ot < 4; ++ot)
            #pragma unroll
            for (int r = 0; r < 16; ++r)
                Red[((mt * 4 + ot) * 16 + r) * 64 + lane] = acc[ot][r];
    }
    __syncthreads();
    if (h == 0) {
        float be2c[4][8], bsc[4];
        #pragma unroll
        for (int ot = 0; ot < 4; ++ot) {
            int o = 32 * ot + l31;
            bsc[ot] = bs2[o] + bs2[128 + o];
            #pragma unroll
            for (int ee = 0; ee < 8; ++ee) be2c[ot][ee] = be2[ee * 128 + o];
        }
        const float* mgb = mgs + (32 * mt) * 8;
        #pragma unroll
        for (int r = 0; r < 16; ++r) {
            int mrow = (r & 3) + 8 * (r >> 2) + 4 * lh;
            f32x4 g0 = *(const f32x4*)&mgb[mrow * 8];
            f32x4 g1 = *(const f32x4*)&mgb[mrow * 8 + 4];
            size_t orow = (size_t)(tok0 + 32 * mt + mrow) * 128;
            #pragma unroll
            for (int ot = 0; ot < 4; ++ot) {
                float b = bsc[ot];
                #pragma unroll
                for (int ee = 0; ee < 4; ++ee) b = fmaf(g0[ee], be2c[ot][ee], b);
                #pragma unroll
                for (int ee = 0; ee < 4; ++ee) b = fmaf(g1[ee], be2c[ot][4 + ee], b);
                float v = acc[ot][r] + Red[((mt * 4 + ot) * 16 + r) * 64 + lane] + b;
                out[orow + 32 * ot + l31] = v;
            }
        }
    }
}

// ---------------------------------------------------------------------------
extern "C" void kernel_launch(void* const* d_in, const int* in_sizes, int n_in,
                              void* d_out, int out_size, void* d_ws, size_t ws_size,
                              hipStream_t stream)
{
    const float* x   = (const float*)d_in[0];
    const float* Wr1 = (const float*)d_in[1];
    const float* br1 = (const float*)d_in[2];
    const float* Wr2 = (const float*)d_in[3];
    const float* br2 = (const float*)d_in[4];
    const float* We1 = (const float*)d_in[5];
    const float* be1 = (const float*)d_in[6];
    const float* We2 = (const float*)d_in[7];
    const float* be2 = (const float*)d_in[8];
    const float* Ws1 = (const float*)d_in[9];
    const float* bs1 = (const float*)d_in[10];
    const float* Ws2 = (const float*)d_in[11];
    const float* bs2 = (const float*)d_in[12];

    __bf16* w1p  = (__bf16*)d_ws;
    __bf16* w2p  = (__bf16*)((char*)d_ws + 368640);
    double* wr1d = (double*)((char*)d_ws + 696320);
    double* wr2d = (double*)((char*)d_ws + 712704);
    double* br1d = (double*)((char*)d_ws + 713728);
    double* br2d = (double*)((char*)d_ws + 713856);

    pack_kernel<<<179, 256, 0, stream>>>(We1, be1, Ws1, bs1, We2, Ws2,
                                         Wr1, br1, Wr2, br2,
                                         w1p, w2p, wr1d, br1d, wr2d, br2d);
    moe_main_kernel<<<1024, 256, 0, stream>>>(x, wr1d, br1d, wr2d, br2d,
                                              w1p, w2p, be2, bs2, (float*)d_out);
}